// Round 4
// baseline (237.997 us; speedup 1.0000x reference)
//
#include <hip/hip_runtime.h>
#include <hip/hip_cooperative_groups.h>
#include <stdint.h>

namespace cg = cooperative_groups;

#define NBINS 1000
#define GRID 256
#define BLK 512
#define HISTOFF 4096  // uint offset of global histograms in W

// ---- sortable encoding for f32 min/max ----
__device__ __forceinline__ unsigned enc_f32(float f) {
    unsigned b = __float_as_uint(f);
    return (b & 0x80000000u) ? ~b : (b | 0x80000000u);
}
__device__ __forceinline__ float dec_f32(unsigned e) {
    unsigned b = (e & 0x80000000u) ? (e ^ 0x80000000u) : ~e;
    return __uint_as_float(b);
}

// count of v <= x_j == sum_{k<=j} hist[k] with bin k = clamp(ceil((v-lo)/dx))
__device__ __forceinline__ int binof(float v, float lo, float inv_dx) {
    float u = (v - lo) * inv_dx;
    int k = (int)ceilf(u);
    return min(max(k, 0), NBINS - 1);
}

#define MM1(v) { unsigned e = enc_f32(v); emin = min(emin, e); emax = max(emax, e); }
#define MM4(q) { MM1(q.x) MM1(q.y) MM1(q.z) MM1(q.w) }

// W layout (uints): [0..GRID)=per-block min, [GRID..2*GRID)=per-block max,
//                   [HISTOFF..HISTOFF+2*NBINS)=global histograms (p then t)
__global__ void __launch_bounds__(BLK) crps_fused(
        const float* __restrict__ p, const float* __restrict__ t,
        long long n, unsigned* __restrict__ W, float* __restrict__ out) {
    cg::grid_group grid = cg::this_grid();

    __shared__ __align__(16) unsigned h[8 * NBINS];  // 32 KB hist copies / reused in phase 3
    __shared__ unsigned sA[BLK];
    __shared__ unsigned sB[BLK];

    const int tid = threadIdx.x;
    const int bid = blockIdx.x;

    // zero this block's slice of the global histogram region (no init kernel)
    {
        int base = bid * 8;
        if (tid < 8) {
            int j = base + tid;
            if (j < 2 * NBINS) W[HISTOFF + j] = 0u;
        }
    }

    long long n4 = n >> 2;
    const float4* p4 = (const float4*)p;
    const float4* t4 = (const float4*)t;
    long long idx = (long long)bid * BLK + tid;
    long long stride = (long long)GRID * BLK;

    // ---------------- phase 1: min/max ----------------
    unsigned emin = 0xFFFFFFFFu, emax = 0u;
    {
        long long i = idx;
        for (; i + 3 * stride < n4; i += 4 * stride) {
            float4 a0 = p4[i];
            float4 a1 = p4[i + stride];
            float4 a2 = p4[i + 2 * stride];
            float4 a3 = p4[i + 3 * stride];
            float4 b0 = t4[i];
            float4 b1 = t4[i + stride];
            float4 b2 = t4[i + 2 * stride];
            float4 b3 = t4[i + 3 * stride];
            MM4(a0) MM4(a1) MM4(a2) MM4(a3)
            MM4(b0) MM4(b1) MM4(b2) MM4(b3)
        }
        for (; i < n4; i += stride) {
            float4 a = p4[i];
            float4 b = t4[i];
            MM4(a) MM4(b)
        }
        for (long long j = (n4 << 2) + idx; j < n; j += stride) {
            MM1(p[j]) MM1(t[j])
        }
    }
    sA[tid] = emin; sB[tid] = emax;
    __syncthreads();
    for (int s = BLK / 2; s > 0; s >>= 1) {
        if (tid < s) {
            sA[tid] = min(sA[tid], sA[tid + s]);
            sB[tid] = max(sB[tid], sB[tid + s]);
        }
        __syncthreads();
    }
    if (tid == 0) { W[bid] = sA[0]; W[GRID + bid] = sB[0]; }

    grid.sync();

    // ---- every block redundantly reduces the per-block slots (from L2) ----
    unsigned ge_min = (tid < GRID) ? W[tid] : 0xFFFFFFFFu;
    unsigned ge_max = (tid < GRID) ? W[GRID + tid] : 0u;
    sA[tid] = ge_min; sB[tid] = ge_max;
    __syncthreads();
    for (int s = BLK / 2; s > 0; s >>= 1) {
        if (tid < s) {
            sA[tid] = min(sA[tid], sA[tid + s]);
            sB[tid] = max(sB[tid], sB[tid + s]);
        }
        __syncthreads();
    }
    float lo = dec_f32(sA[0]);
    float hi = dec_f32(sB[0]);
    float inv_dx = (float)(NBINS - 1) / (hi - lo);
    __syncthreads();

    // ---------------- phase 2: histogram ----------------
    // 4 LDS sub-copies per histogram (lane&3); copy stride 1000 words = 8-bank
    // rotation so the 4 copies of one bin hit banks {0,8,16,24}.
    for (int i2 = tid; i2 < 8 * NBINS; i2 += BLK) h[i2] = 0u;
    __syncthreads();
    int cpo = (tid & 3) * NBINS;
    int cto = cpo + 4 * NBINS;
    {
        long long i = idx;
        for (; i + stride < n4; i += 2 * stride) {
            float4 a0 = p4[i];
            float4 a1 = p4[i + stride];
            float4 b0 = t4[i];
            float4 b1 = t4[i + stride];
            atomicAdd(&h[cpo + binof(a0.x, lo, inv_dx)], 1u);
            atomicAdd(&h[cpo + binof(a0.y, lo, inv_dx)], 1u);
            atomicAdd(&h[cpo + binof(a0.z, lo, inv_dx)], 1u);
            atomicAdd(&h[cpo + binof(a0.w, lo, inv_dx)], 1u);
            atomicAdd(&h[cpo + binof(a1.x, lo, inv_dx)], 1u);
            atomicAdd(&h[cpo + binof(a1.y, lo, inv_dx)], 1u);
            atomicAdd(&h[cpo + binof(a1.z, lo, inv_dx)], 1u);
            atomicAdd(&h[cpo + binof(a1.w, lo, inv_dx)], 1u);
            atomicAdd(&h[cto + binof(b0.x, lo, inv_dx)], 1u);
            atomicAdd(&h[cto + binof(b0.y, lo, inv_dx)], 1u);
            atomicAdd(&h[cto + binof(b0.z, lo, inv_dx)], 1u);
            atomicAdd(&h[cto + binof(b0.w, lo, inv_dx)], 1u);
            atomicAdd(&h[cto + binof(b1.x, lo, inv_dx)], 1u);
            atomicAdd(&h[cto + binof(b1.y, lo, inv_dx)], 1u);
            atomicAdd(&h[cto + binof(b1.z, lo, inv_dx)], 1u);
            atomicAdd(&h[cto + binof(b1.w, lo, inv_dx)], 1u);
        }
        for (; i < n4; i += stride) {
            float4 a = p4[i];
            float4 b = t4[i];
            atomicAdd(&h[cpo + binof(a.x, lo, inv_dx)], 1u);
            atomicAdd(&h[cpo + binof(a.y, lo, inv_dx)], 1u);
            atomicAdd(&h[cpo + binof(a.z, lo, inv_dx)], 1u);
            atomicAdd(&h[cpo + binof(a.w, lo, inv_dx)], 1u);
            atomicAdd(&h[cto + binof(b.x, lo, inv_dx)], 1u);
            atomicAdd(&h[cto + binof(b.y, lo, inv_dx)], 1u);
            atomicAdd(&h[cto + binof(b.z, lo, inv_dx)], 1u);
            atomicAdd(&h[cto + binof(b.w, lo, inv_dx)], 1u);
        }
        for (long long j = (n4 << 2) + idx; j < n; j += stride) {
            atomicAdd(&h[cpo + binof(p[j], lo, inv_dx)], 1u);
            atomicAdd(&h[cto + binof(t[j], lo, inv_dx)], 1u);
        }
    }
    __syncthreads();
    {
        unsigned* Wh = W + HISTOFF;
        for (int b = tid; b < NBINS; b += BLK) {
            unsigned sp = h[b] + h[NBINS + b] + h[2 * NBINS + b] + h[3 * NBINS + b];
            unsigned st = h[4 * NBINS + b] + h[5 * NBINS + b] + h[6 * NBINS + b] + h[7 * NBINS + b];
            if (sp) atomicAdd(&Wh[b], sp);
            if (st) atomicAdd(&Wh[NBINS + b], st);
        }
    }

    grid.sync();

    // ---------------- phase 3: block 0 scans + trapz ----------------
    if (bid != 0) return;

    const unsigned* Hp = W + HISTOFF;
    const unsigned* Ht = W + HISTOFF + NBINS;
    int j0 = 2 * tid, j1 = 2 * tid + 1;
    unsigned hp0 = (j0 < NBINS) ? Hp[j0] : 0u;
    unsigned hp1 = (j1 < NBINS) ? Hp[j1] : 0u;
    unsigned ht0 = (j0 < NBINS) ? Ht[j0] : 0u;
    unsigned ht1 = (j1 < NBINS) ? Ht[j1] : 0u;

    // inclusive scan over pair-sums (P)
    sA[tid] = hp0 + hp1;
    __syncthreads();
    for (int off = 1; off < BLK; off <<= 1) {
        unsigned v = (tid >= off) ? sA[tid - off] : 0u;
        __syncthreads();
        sA[tid] += v;
        __syncthreads();
    }
    unsigned exP = sA[tid] - (hp0 + hp1);
    __syncthreads();
    // inclusive scan over pair-sums (T)
    sA[tid] = ht0 + ht1;
    __syncthreads();
    for (int off = 1; off < BLK; off <<= 1) {
        unsigned v = (tid >= off) ? sA[tid - off] : 0u;
        __syncthreads();
        sA[tid] += v;
        __syncthreads();
    }
    unsigned exT = sA[tid] - (ht0 + ht1);

    float invn = 1.0f / (float)n;
    double acc = 0.0;
    if (j0 < NBINS) {
        unsigned cp = exP + hp0, ct = exT + ht0;
        float d = (float)cp * invn - (float)ct * invn;
        float w = (j0 == 0 || j0 == NBINS - 1) ? 0.5f : 1.0f;
        acc += (double)(d * d) * (double)w;
    }
    if (j1 < NBINS) {
        unsigned cp = exP + hp0 + hp1, ct = exT + ht0 + ht1;
        float d = (float)cp * invn - (float)ct * invn;
        float w = (j1 == 0 || j1 == NBINS - 1) ? 0.5f : 1.0f;
        acc += (double)(d * d) * (double)w;
    }
    double* rd = (double*)h;  // h unused in phase 3; 16B-aligned
    rd[tid] = acc;
    __syncthreads();
    for (int s = BLK / 2; s > 0; s >>= 1) {
        if (tid < s) rd[tid] += rd[tid + s];
        __syncthreads();
    }
    if (tid == 0) {
        double dx = (double)(hi - lo) / (double)(NBINS - 1);
        out[0] = (float)(rd[0] * dx);
    }
}

extern "C" void kernel_launch(void* const* d_in, const int* in_sizes, int n_in,
                              void* d_out, int out_size, void* d_ws, size_t ws_size,
                              hipStream_t stream) {
    const float* p = (const float*)d_in[0];
    const float* t = (const float*)d_in[1];
    float* out = (float*)d_out;
    long long n = (long long)in_sizes[0];
    unsigned* W = (unsigned*)d_ws;

    void* args[] = { (void*)&p, (void*)&t, (void*)&n, (void*)&W, (void*)&out };
    hipLaunchCooperativeKernel((const void*)crps_fused, dim3(GRID), dim3(BLK),
                               args, 0, stream);
}